// Round 14
// baseline (190.672 us; speedup 1.0000x reference)
//
#include <hip/hip_runtime.h>

// ---------------------------------------------------------------------------
// MultiHeadAttention with clipped relative-position embeddings (q/k/v-side).
// B=4, L=1024, D=1024, N=16, H=64, E=64 (127 distinct distances).
//
// Pipeline:
//   0. convert_kernel : region-dispatched, all-coalesced (validated r12)
//   1. gemm_qkv       : QKV GEMM + XCD-grouped block swizzle (A-panels
//                       L2-resident per XCD); q/k coalesced scatter; v ->
//                       v_t via LDS transpose (validated r12)
//   2. proj_kernel    : q_proj + k_proj in one launch (+ kp_edge)
//   3. attn_kernel    : r13 async-DMA structure (validated 88 us) +
//                       s_setprio(1) around MFMA clusters (T5, m191)
//   4. gemm_n64       : out-proj 128x64 tiles + XCD swizzle -> fp32 d_out
// Workspace 72.3 MB (attn_o aliased onto dead x_bf; validated).
// ---------------------------------------------------------------------------

typedef __bf16 bf16x8 __attribute__((ext_vector_type(8)));
typedef float f32x4 __attribute__((ext_vector_type(4)));
typedef unsigned int u32x4 __attribute__((ext_vector_type(4)));
typedef unsigned short u16x4 __attribute__((ext_vector_type(4)));

__device__ __forceinline__ unsigned short f2bf(float f) {
    unsigned int u = __builtin_bit_cast(unsigned int, f);
    u += 0x7fffu + ((u >> 16) & 1u);          // RNE
    return (unsigned short)(u >> 16);
}
__device__ __forceinline__ float bf2f(unsigned short s) {
    unsigned int u = ((unsigned int)s) << 16;
    return __builtin_bit_cast(float, u);
}

// async global->LDS, 16 bytes per lane; LDS dest must be wave-uniform base
__device__ __forceinline__ void gl2lds16(const unsigned short* g, unsigned short* l) {
    __builtin_amdgcn_global_load_lds(
        (const __attribute__((address_space(1))) unsigned int*)g,
        (__attribute__((address_space(3))) unsigned int*)l, 16, 0, 0);
}

// ---------------------------------------------------------------------------
// Convert / relayout kernel — all regions coalesced (validated r12).
// ---------------------------------------------------------------------------
__global__ __launch_bounds__(256) void convert_kernel(
    const float* __restrict__ x,
    const float* __restrict__ wq,
    const float* __restrict__ wk,
    const float* __restrict__ wv,
    const float* __restrict__ wo,
    const float* __restrict__ qe,
    const float* __restrict__ ke,
    const float* __restrict__ ve,
    unsigned short* __restrict__ x_bf,
    unsigned short* __restrict__ wqkv_bt,
    unsigned short* __restrict__ wo_bt,
    unsigned short* __restrict__ qe_bf,
    unsigned short* __restrict__ ke_bf,
    unsigned short* __restrict__ ve_t)
{
    __shared__ unsigned short T[64 * 72];
    const int bid = blockIdx.x;
    const int tid = threadIdx.x;

    if (bid < 512) {
        const float* src = x + (size_t)bid * 8192;
        unsigned short* dst = x_bf + (size_t)bid * 8192;
#pragma unroll
        for (int c = 0; c < 8; ++c) {
            int idx = c * 1024 + tid * 4;
            f32x4 v = *reinterpret_cast<const f32x4*>(src + idx);
            u16x4 o = u16x4{f2bf(v[0]), f2bf(v[1]), f2bf(v[2]), f2bf(v[3])};
            *reinterpret_cast<u16x4*>(dst + idx) = o;
        }
    } else if (bid < 1280) {
        int t = bid - 512;
        int which = t >> 8, n = (t >> 4) & 15, dt = t & 15;
        const float* w = which == 0 ? wq : which == 1 ? wk : wv;
        const float* src = w + ((size_t)n * 1024 + dt * 64) * 64;   // [dd][hh]
#pragma unroll
        for (int c = 0; c < 4; ++c) {
            int chunk = c * 256 + tid;             // 1024 chunks of 4 f32
            int dd = chunk >> 4, hh = (chunk & 15) * 4;
            f32x4 v = *reinterpret_cast<const f32x4*>(src + dd * 64 + hh);
#pragma unroll
            for (int j = 0; j < 4; ++j) T[(hh + j) * 72 + dd] = f2bf(v[j]);
        }
        __syncthreads();
        unsigned short* dstb = wqkv_bt + ((size_t)(which * 1024 + n * 64)) * 1024 + dt * 64;
#pragma unroll
        for (int c = 0; c < 2; ++c) {
            int chunk = c * 256 + tid;             // 512 chunks of 8
            int h = chunk >> 3, d8 = (chunk & 7) * 8;
            u32x4 v = *reinterpret_cast<const u32x4*>(&T[h * 72 + d8]);
            *reinterpret_cast<u32x4*>(dstb + (size_t)h * 1024 + d8) = v;
        }
    } else if (bid < 1536) {
        int t = bid - 1280;
        int n = t >> 4, mt = t & 15;
        const float* src = wo + (size_t)n * 64 * 1024 + mt * 64;    // [hh][mm]
#pragma unroll
        for (int c = 0; c < 4; ++c) {
            int chunk = c * 256 + tid;             // 1024 chunks of 4 f32
            int hh = chunk >> 4, mm = (chunk & 15) * 4;
            f32x4 v = *reinterpret_cast<const f32x4*>(src + (size_t)hh * 1024 + mm);
#pragma unroll
            for (int j = 0; j < 4; ++j) T[(mm + j) * 72 + hh] = f2bf(v[j]);
        }
        __syncthreads();
        unsigned short* dstb = wo_bt + (size_t)(mt * 64) * 1024 + n * 64;
#pragma unroll
        for (int c = 0; c < 2; ++c) {
            int chunk = c * 256 + tid;             // 512 chunks of 8
            int m = chunk >> 3, h8 = (chunk & 7) * 8;
            u32x4 v = *reinterpret_cast<const u32x4*>(&T[m * 72 + h8]);
            *reinterpret_cast<u32x4*>(dstb + (size_t)m * 1024 + h8) = v;
        }
    } else {
        for (int i = tid; i < 8192; i += 256) {
            int e = i >> 6;
            qe_bf[i] = (e < 127) ? f2bf(qe[i]) : 0;
            ke_bf[i] = (e < 127) ? f2bf(ke[i]) : 0;
            int h = i >> 7, e2 = i & 127;
            ve_t[i] = (e2 < 127) ? f2bf(ve[e2 * 64 + h]) : 0;
        }
    }
}

// ---------------------------------------------------------------------------
// QKV GEMM (validated r12) + XCD-grouped 1D swizzle: 768 blocks, XCD x owns
// m-rows [x*4, x*4+4) -> A panels (1 MB) L2-resident, reused 24x.
// ---------------------------------------------------------------------------
__global__ __launch_bounds__(256) void gemm_qkv_kernel(
    const unsigned short* __restrict__ A,
    const unsigned short* __restrict__ Bt,
    unsigned short* __restrict__ q_buf,
    unsigned short* __restrict__ k_buf,
    unsigned short* __restrict__ v_t)
{
    __shared__ unsigned short Sh[2 * 128 * 64];    // As | Bs; reused as T[128][128]
    unsigned short* As = Sh;
    unsigned short* Bs = Sh + 8192;
    const int id = blockIdx.x;                     // 768 = 8 XCD * 96
    const int swz = (id & 7) * 96 + (id >> 3);     // bijective (768 % 8 == 0)
    const int m0 = (swz / 24) * 128;
    const int n0 = (swz % 24) * 128;
    const int tid = threadIdx.x;
    const int lane = tid & 63;
    const int w = tid >> 6;
    const int wr = w >> 1, wc = w & 1;
    const int g = lane >> 4, c16 = lane & 15;

    f32x4 acc[4][4];
#pragma unroll
    for (int i = 0; i < 4; ++i)
#pragma unroll
        for (int j = 0; j < 4; ++j) acc[i][j] = f32x4{0.f, 0.f, 0.f, 0.f};

    for (int kt = 0; kt < 1024; kt += 64) {
#pragma unroll
        for (int c = 0; c < 4; ++c) {
            int chunk = c * 256 + tid;           // 1024 chunks of 16B
            int row = chunk >> 3, col = (chunk & 7) * 8;
            unsigned short* ldsA = &As[(c * 256 + w * 64) * 8];   // wave-uniform
            unsigned short* ldsB = &Bs[(c * 256 + w * 64) * 8];
            gl2lds16(A  + (size_t)(m0 + row) * 1024 + kt + col, ldsA);
            gl2lds16(Bt + (size_t)(n0 + row) * 1024 + kt + col, ldsB);
        }
        __syncthreads();
#pragma unroll
        for (int ks = 0; ks < 2; ++ks) {
            bf16x8 af[4], bfr[4];
#pragma unroll
            for (int mi = 0; mi < 4; ++mi)
                af[mi] = __builtin_bit_cast(bf16x8,
                    *reinterpret_cast<const u32x4*>(&As[(wr * 64 + mi * 16 + c16) * 64 + ks * 32 + g * 8]));
#pragma unroll
            for (int ni = 0; ni < 4; ++ni)
                bfr[ni] = __builtin_bit_cast(bf16x8,
                    *reinterpret_cast<const u32x4*>(&Bs[(wc * 64 + ni * 16 + c16) * 64 + ks * 32 + g * 8]));
#pragma unroll
            for (int mi = 0; mi < 4; ++mi)
#pragma unroll
                for (int ni = 0; ni < 4; ++ni)
                    acc[mi][ni] = __builtin_amdgcn_mfma_f32_16x16x32_bf16(af[mi], bfr[ni], acc[mi][ni], 0, 0, 0);
        }
        __syncthreads();
    }

    if (n0 < 2048) {
#pragma unroll
        for (int mi = 0; mi < 4; ++mi)
#pragma unroll
            for (int ni = 0; ni < 4; ++ni)
#pragma unroll
                for (int r = 0; r < 4; ++r) {
                    int m = m0 + wr * 64 + mi * 16 + g * 4 + r;
                    int c = n0 + wc * 64 + ni * 16 + c16;
                    int b = m >> 10, l = m & 1023;
                    int which = c >> 10, n = (c >> 6) & 15, h = c & 63;
                    unsigned short* dst = which == 0 ? q_buf : k_buf;
                    dst[(((size_t)b * 16 + n) * 1024 + l) * 64 + h] = f2bf(acc[mi][ni][r]);
                }
    } else {
#pragma unroll
        for (int mi = 0; mi < 4; ++mi)
#pragma unroll
            for (int ni = 0; ni < 4; ++ni)
#pragma unroll
                for (int r = 0; r < 4; ++r) {
                    int l = wr * 64 + mi * 16 + g * 4 + r;
                    int cr = wc * 64 + ni * 16 + c16;
                    Sh[cr * 128 + (l ^ ((cr & 7) << 3))] = f2bf(acc[mi][ni][r]);
                }
        __syncthreads();
        const int b = m0 >> 10;
        const size_t rowbase = (size_t)(b * 1024 + (n0 - 2048)) * 1024 + (m0 & 1023);
#pragma unroll
        for (int c = 0; c < 8; ++c) {
            int chunk = c * 256 + tid;           // 2048 chunks of 8
            int cr = chunk >> 4, l0 = (chunk & 15) * 8;
            int lsw = l0 ^ ((cr & 7) << 3);
            u32x4 vv = *reinterpret_cast<const u32x4*>(&Sh[cr * 128 + lsw]);
            *reinterpret_cast<u32x4*>(v_t + rowbase + (size_t)cr * 1024 + l0) = vv;
        }
    }
}

// ---------------------------------------------------------------------------
// Merged q_proj / k_proj: grid (1, 1024); by<512 -> q, else k (+ kp_edge).
// ---------------------------------------------------------------------------
__global__ __launch_bounds__(256) void proj_kernel(
    const unsigned short* __restrict__ q_buf,
    const unsigned short* __restrict__ k_buf,
    const unsigned short* __restrict__ qe_bf,   // [128][64], row 127 = 0
    const unsigned short* __restrict__ ke_bf,
    unsigned short* __restrict__ q_proj,        // [65536][128]
    unsigned short* __restrict__ k_proj,
    unsigned short* __restrict__ kp_edge)       // [2][65536]
{
    __shared__ unsigned short As[128 * 64];
    __shared__ unsigned short Bs[128 * 64];
    const int by = blockIdx.y;
    const int which = by >> 9;                  // 0 = q, 1 = k
    const int m0 = (by & 511) * 128;
    const unsigned short* A  = which ? k_buf : q_buf;
    const unsigned short* Bt = which ? ke_bf : qe_bf;
    unsigned short* C0 = which ? k_proj : q_proj;

    const int tid = threadIdx.x;
    const int lane = tid & 63;
    const int w = tid >> 6;
    const int wr = w >> 1, wc = w & 1;
    const int g = lane >> 4, c16 = lane & 15;

    f32x4 acc[4][4];
#pragma unroll
    for (int i = 0; i < 4; ++i)
#pragma unroll
        for (int j = 0; j < 4; ++j) acc[i][j] = f32x4{0.f, 0.f, 0.f, 0.f};

#pragma unroll
    for (int c = 0; c < 4; ++c) {
        int chunk = c * 256 + tid;               // 1024 chunks of 16B
        int row = chunk >> 3, col = (chunk & 7) * 8;
        unsigned short* ldsA = &As[(c * 256 + w * 64) * 8];   // wave-uniform
        unsigned short* ldsB = &Bs[(c * 256 + w * 64) * 8];
        gl2lds16(A  + (size_t)(m0 + row) * 64 + col, ldsA);
        gl2lds16(Bt + (size_t)row * 64 + col, ldsB);
    }
    __syncthreads();
#pragma unroll
    for (int ks = 0; ks < 2; ++ks) {
        bf16x8 af[4], bfr[4];
#pragma unroll
        for (int mi = 0; mi < 4; ++mi)
            af[mi] = __builtin_bit_cast(bf16x8,
                *reinterpret_cast<const u32x4*>(&As[(wr * 64 + mi * 16 + c16) * 64 + ks * 32 + g * 8]));
#pragma unroll
        for (int ni = 0; ni < 4; ++ni)
            bfr[ni] = __builtin_bit_cast(bf16x8,
                *reinterpret_cast<const u32x4*>(&Bs[(wc * 64 + ni * 16 + c16) * 64 + ks * 32 + g * 8]));
#pragma unroll
        for (int mi = 0; mi < 4; ++mi)
#pragma unroll
            for (int ni = 0; ni < 4; ++ni)
                acc[mi][ni] = __builtin_amdgcn_mfma_f32_16x16x32_bf16(af[mi], bfr[ni], acc[mi][ni], 0, 0, 0);
    }

#pragma unroll
    for (int mi = 0; mi < 4; ++mi) {
#pragma unroll
        for (int ni = 0; ni < 4; ++ni) {
#pragma unroll
            for (int r = 0; r < 4; ++r) {
                int m = m0 + wr * 64 + mi * 16 + g * 4 + r;
                int c = wc * 64 + ni * 16 + c16;          // n0 = 0, N = 128
                float v = acc[mi][ni][r];
                C0[(size_t)m * 128 + c] = f2bf(v);
                if (which && (c == 0 || c == 126))
                    kp_edge[(size_t)(c ? 65536 : 0) + m] = f2bf(v);
            }
        }
    }
}

// ---------------------------------------------------------------------------
// Out-projection GEMM: [4096,1024] @ wo_bt^T -> fp32, 128x64 tiles,
// XCD-grouped 1D swizzle (512 blocks -> 4 m-rows per XCD).
// ---------------------------------------------------------------------------
__global__ __launch_bounds__(256) void gemm_n64_kernel(
    const unsigned short* __restrict__ A,       // [4096][1024] bf16
    const unsigned short* __restrict__ Bt,      // [1024][1024] bf16
    float* __restrict__ C)                      // [4096][1024] fp32
{
    __shared__ unsigned short As[128 * 64];
    __shared__ unsigned short Bs[64 * 64];
    const int id = blockIdx.x;                  // 512 = 8 XCD * 64
    const int swz = (id & 7) * 64 + (id >> 3);  // bijective (512 % 8 == 0)
    const int m0 = (swz >> 4) * 128;
    const int n0 = (swz & 15) * 64;
    const int tid = threadIdx.x;
    const int lane = tid & 63;
    const int w = tid >> 6;
    const int g = lane >> 4, c16 = lane & 15;

    f32x4 acc[2][4];
#pragma unroll
    for (int i = 0; i < 2; ++i)
#pragma unroll
        for (int j = 0; j < 4; ++j) acc[i][j] = f32x4{0.f, 0.f, 0.f, 0.f};

    for (int kt = 0; kt < 1024; kt += 64) {
#pragma unroll
        for (int c = 0; c < 4; ++c) {            // A: 1024 chunks of 16B
            int chunk = c * 256 + tid;
            int row = chunk >> 3, col = (chunk & 7) * 8;
            unsigned short* ldsA = &As[(c * 256 + w * 64) * 8];
            gl2lds16(A + (size_t)(m0 + row) * 1024 + kt + col, ldsA);
        }
#pragma unroll
        for (int c = 0; c < 2; ++c) {            // B: 512 chunks of 16B
            int chunk = c * 256 + tid;
            int row = chunk >> 3, col = (chunk & 7) * 8;
            unsigned short* ldsB = &Bs[(c * 256 + w * 64) * 8];
            gl2lds16(Bt + (size_t)(n0 + row) * 1024 + kt + col, ldsB);
        }
        __syncthreads();
#pragma unroll
        for (int ks = 0; ks < 2; ++ks) {
            bf16x8 af[2], bfr[4];
#pragma unroll
            for (int mi = 0; mi < 2; ++mi)
                af[mi] = __builtin_bit_cast(bf16x8,
                    *reinterpret_cast<const u32x4*>(&As[(w * 32 + mi * 16 + c16) * 64 + ks * 32 + g * 8]));
#pragma unroll
            for (int ni = 0; ni < 4; ++ni)
                bfr[ni] = __builtin_bit_cast(bf16x8,
                    *reinterpret_cast<const u32x4*>(&Bs[(ni * 16 + c16) * 64 + ks * 32 + g * 8]));
#pragma unroll
            for (int mi = 0; mi < 2; ++mi)
#pragma unroll
                for (int ni = 0; ni < 4; ++ni)
                    acc[mi][ni] = __builtin_amdgcn_mfma_f32_16x16x32_bf16(af[mi], bfr[ni], acc[mi][ni], 0, 0, 0);
        }
        __syncthreads();
    }

#pragma unroll
    for (int mi = 0; mi < 2; ++mi)
#pragma unroll
        for (int ni = 0; ni < 4; ++ni)
#pragma unroll
            for (int r = 0; r < 4; ++r) {
                int m = m0 + w * 32 + mi * 16 + g * 4 + r;
                int cc = n0 + ni * 16 + c16;
                C[(size_t)m * 1024 + cc] = acc[mi][ni][r];
            }
}

// ---------------------------------------------------------------------------
// Fused attention — r13 structure (validated 88 us) + T5 setprio.
// 512 threads (8 waves), QBLK=128, KVBLK=64, grid 512; async DMA staging.
// LDS 68352 B, 2 blocks/CU. 1 barrier/tile steady; kp tiles take one extra.
// ---------------------------------------------------------------------------
#define ATTN_LDS_BYTES 68352

__global__ __launch_bounds__(512, 4) void attn_kernel(
    const unsigned short* __restrict__ q_buf,   // [B,N,L,H] bf16
    const unsigned short* __restrict__ k_buf,   // [B,N,L,H] bf16
    const unsigned short* __restrict__ v_t,     // [B,N,H,L] bf16
    const unsigned short* __restrict__ q_proj,  // [B,N,L,128] bf16
    const unsigned short* __restrict__ k_proj,  // [B,N,L,128] bf16
    const unsigned short* __restrict__ kp_edge, // [2][65536] bf16 (e=0,126)
    const unsigned short* __restrict__ ve_t,    // [64][128] bf16 (col 127 = 0)
    const int* __restrict__ mask,               // [B,1024]
    unsigned short* __restrict__ attn_out)      // [B,L,N,H] bf16
{
    extern __shared__ char smem[];
    unsigned short* Ps   = (unsigned short*)(smem + 32768); // [128][72]
    unsigned short* kp   = (unsigned short*)(smem + 51200); // [64][128]
    int*            mjI  = (int*)(smem + 67584);            // [2][64]
    unsigned short* kpeU = (unsigned short*)(smem + 68096); // [2][64]
    unsigned short* veT = (unsigned short*)smem;            // [64][136] overlay
    unsigned short* peB = (unsigned short*)(smem + 17408);  // [128][136] overlay
    float* lrow = (float*)(smem + 52224);                   // [128]

    const int id = blockIdx.x;
    const int bn = id & 63;                  // = b*16 + n (same XCD per group)
    const int ib = id >> 6;                  // i-block, 128 rows
    const int b = bn >> 4;
    const int i0 = ib * 128;
    const int tid = threadIdx.x;
    const int lane = tid & 63;
    const int w = tid >> 6;                  // wave 0..7, rows [w*16,w*16+16)
    const int g = lane >> 4, c16 = lane & 15;
    const int il = tid >> 2;                 // histogram row 0..127
    const int part = tid & 3;                // bins [part*32, part*32+32)
    const int swz = c16 & 7;                 // fragment-read chunk XOR

    const int jlo = 2 * ib - 1, jhi = 2 * ib + 2;   // kp window

    // DMA geometry: wave w covers rows [w*8, w*8+8) of a [64][128B] tile
    const int srow = w * 8 + (lane >> 3);
    const int gch  = (lane & 7) ^ (srow & 7);       // pre-swizzled chunk

    auto issue_kv = [&](int j0n, int nxt) {
        gl2lds16(k_buf + ((size_t)bn * 1024 + j0n + srow) * 64 + gch * 8,
                 (unsigned short*)(smem + nxt * 8192) + w * 512);
        gl2lds16(v_t + ((size_t)bn * 64 + srow) * 1024 + j0n + gch * 8,
                 (unsigned short*)(smem + 16384 + nxt * 8192) + w * 512);
    };
    auto stage_scalar = [&](int jtn, int nxt) {     // waves 0/1, plain ld+st
        int j0n = jtn * 64;
        if (w == 0) mjI[nxt * 64 + lane] = mask[b * 1024 + j0n + lane];
        if (w == 1) kpeU[nxt * 64 + lane] =
            kp_edge[(size_t)(jtn < 2 * ib ? 65536 : 0) + bn * 1024 + j0n + lane];
    };
    auto issue_kp = [&](int jtn) {                  // [64][128] linear, 16 KB
        int j0n = jtn * 64;
#pragma unroll
        for (int c = 0; c < 2; ++c) {
            int chunk = w * 128 + c * 64 + lane;
            int row = chunk >> 4, col8 = chunk & 15;
            gl2lds16(k_proj + ((size_t)bn * 1024 + j0n + row) * 128 + col8 * 8,
                     kp + (w * 128 + c * 64) * 8);
        }
    };

    // prologue: tile 0 in flight
    issue_kv(0, 0);
    stage_scalar(0, 0);
    if (0 >= jlo && 0 <= jhi) issue_kp(0);

    // Q fragments + loop-invariant qp edge columns (overlap tile-0 latency)
    bf16x8 qf[2];
    {
        const unsigned short* qrow = q_buf + ((size_t)bn * 1024 + i0 + w * 16 + c16) * 64;
        qf[0] = __builtin_bit_cast(bf16x8, *reinterpret_cast<const u32x4*>(qrow + g * 8));
        qf[1] = __builtin_bit_cast(bf16x8, *reinterpret_cast<const u32x4*>(qrow + 32 + g * 8));
    }
    f32x4 qp0v, qp126v;
#pragma unroll
    for (int r = 0; r < 4; ++r) {
        size_t row = (size_t)bn * 1024 + i0 + w * 16 + g * 4 + r;
        qp0v[r]   = 0.125f * bf2f(q_proj[row * 128 + 0]);
        qp126v[r] = 0.125f * bf2f(q_proj[row * 128 + 126]);
    }

    float peR[32];
#pragma unroll
    for (int k = 0; k < 32; ++k) peR[k] = 0.f;
    float lreg = 0.f, acc0 = 0.f, acc126 = 0.f;
    f32x4 accO[4];
#pragma unroll
    for (int i = 0; i < 4; ++i) accO[i] = f32x4{0.f, 0.f, 0.f, 0.f};

    __syncthreads();                          // tile 0 resident

    for (int jt = 0; jt < 16; ++jt) {
        const int cur = jt & 1;
        const int j0 = jt * 64;
        const unsigned short* Ksc = (const unsigned short*)(smem + cur * 8192);
        const unsigned short* Vtc = (const unsigned short*)(smem + 16384 + cur * 8192);

        if (jt < 15) {                        // async prefetch of jt+1
            issue_kv(j0 + 64, cur ^ 1);
            stage_scalar(jt + 1, cur ^ 1);
        }

        // ---- S = Q K^T (swizzled fragment reads) ----
        f32x4 sacc[4];
#pragma unroll
        for (int nf = 0; nf < 4; ++nf) sacc[nf] = f32x4{0.f, 0.f, 0.f, 0.f};
        __builtin_amdgcn_s_setprio(1);
#pragma unroll
        for (int ks = 0; ks < 2; ++ks)
#pragma unroll
            for (int nf = 0; nf < 4; ++nf) {
                bf16x8 kf = __builtin_bit_cast(bf16x8,
                    *reinterpret_cast<const u32x4*>(&Ksc[(nf * 16 + c16) * 64 + ((ks * 4 + g) ^ swz) * 8]));
                sacc[nf] = __builtin_amdgcn_mfma_f32_16x16x32_bf16(qf[ks], kf, sacc[nf], 0, 0, 0);
            }
        __builtin_amdgcn_s_setprio(0);

        // ---- bias + exp + P store (wave-uniform near/far decision) ----
        const int dw = i0 + w * 16 - j0;
        if (dw < 126 && dw > -78) {
            const int d0 = i0 - j0 + 63;
            const unsigned short* qpg = q_proj + ((size_t)bn * 1024 + i0) * 128;
#pragma unroll
            for (int nf = 0; nf < 4; ++nf) {
                int j_l = nf * 16 + c16;
                float mfl = mjI[cur * 64 + j_l] ? 1.f : 0.f;
#pragma unroll
                for (int r = 0; r < 4; ++r) {
                    int i_l = w * 16 + g * 4 + r;
                    int e = d0 + i_l - j_l;
                    e = e < 0 ? 0 : (e > 126 ? 126 : e);
                    float s = sacc[nf][r] + bf2f(kp[j_l * 128 + e]) + bf2f(qpg[i_l * 128 + e]);
                    s *= 0.125f;
                    float p = (mfl > 0.f) ? __expf(s) : 0.f;
                    Ps[i_l * 72 + j_l] = f2bf(p);
                }
            }
        } else {
            const f32x4 qpc = (dw >= 126) ? qp126v : qp0v;
#pragma unroll
            for (int nf = 0; nf < 4; ++nf) {
                int j_l = nf * 16 + c16;
                float kv = 0.125f * bf2f(kpeU[cur * 64 + j_l]);
                float mfl = mjI[cur * 64 + j_l] ? 1.f : 0.f;
#pragma unroll
                for (int r = 0; r < 4; ++r) {
                    float s = sacc[nf][r] * 0.125f + kv + qpc[r];
                    float p = (mfl > 0.f) ? __expf(s) : 0.f;
                    Ps[(w * 16 + g * 4 + r) * 72 + j_l] = f2bf(p);
                }
            }
        }

        // ---- O += P @ V (Ps rows wave-private; lgkmcnt orders RAW) ----
        __builtin_amdgcn_s_setprio(1);
#pragma unroll
        for (int ks = 0; ks < 2; ++ks) {
            bf16x8 pf = __builtin_bit_cast(bf16x8,
                *reinterpret_cast<const u32x4*>(&Ps[(w * 16 + c16) * 72 + ks * 32 + g * 8]));
#pragma unroll
            for (int nf2 = 0; nf2 < 4; ++nf2) {
                bf16x8 vf = __builtin_bit_cast(bf16x8,
                    *reinterpret_cast<const u32x4*>(&Vtc[(nf2 * 16 + c16) * 64 + ((ks * 4 + g) ^ swz) * 8]));
                accO[nf2] = __builtin_amdgcn_mfma_f32_16x16x32_bf16(pf, vf, accO[nf2], 0, 0, 0);
            }
        }
        __builtin_amdgcn_s_setprio(0);

        // ---- pe histogram (register bins; per-row near/far) ----
        {
            bf16x8 s0 = __builtin_bit_cast(bf16x8,
                *reinterpret_cast<const u32x4*>(&Ps[il * 72 + part * 16]));
            bf16x8 s1 = __builtin_bit_cast(bf16x8,
                *reinterpret_cast<const u32x4*>(&Ps[il * 72 + part * 16 + 8]));
            float v[16];
#pragma unroll
            for (int m = 0; m < 8; ++m) { v[m] = (float)s0[m]; v[8 + m] = (float)s1[m]; }
            float rs = 0.f;
#pragma unroll
            for (int m = 0; m < 16; ++m) rs += v[m];
            rs += __shfl_xor(rs, 1);
            rs += __shfl_xor(rs, 2);
            lreg += rs;

            const int base = i0 + il - j0 + 63;   // jl for bin e is base - e
            if (base >= 189) {
                acc126 += rs;
            } else if (base <= 0) {
                acc0 += rs;
            } else {
                float b0 = 0.f, b126 = 0.f;
#pragma unroll
                for (int m = 0; m < 16; ++m) {
                    int jl = part * 16 + m;
                    if (jl >= base) b0 += v[m];
                    if (jl <= base - 126) b126 += v[m];
                }
                b0 += __shfl_xor(b0, 1);     b0 += __shfl_xor(b0, 2);
                b126 += __shfl_xor(b126, 1); b126 += __shfl_xor(b126, 2);
                if (part == 0) peR[0] += b0;
                if (part == 3) peR[30] += b126;
#pragma unroll
                for (int k = 0; k < 32; ++k) {
                    int e = part * 32 + k;
                    int jl = base - e;
                    if (e >= 1 && e <= 125 && jl >= 0 && jl < 64)
                        peR[k] += bf2f(Ps[il * 72 + jl]);
                }
            }
        }

        // ---- end of tile: one barrier; kp-window tiles take an extra ----
        const bool kpn = (jt < 15) && (jt + 1 >= jlo) && (jt + 1 <= jhi);
        __syncthreads();                     // drains prefetch; frees kp/Ps
        if (kpn) {
            issue_kp(jt + 1);                // kp readers (tile jt) done
            __syncthreads();                 // kp(jt+1) resident
        }
    }

    if (part == 0) peR[0] += acc0;
    if (part == 3) peR[30] += acc126;

    // ---- end phase: overlay veT/peB/lrow on dead staging ----
#pragma unroll
    for (int c = 0; c < 2; ++c) {
        int chunk = tid + c * 512;           // 1024 chunks of 8 elems = 64x128
        int h = chunk >> 4, col = (chunk & 15) * 8;
        u32x4 vv = *reinterpret_cast<const u32x4*>(ve_t + h * 128 + col);
        *reinterpret_cast<u32x4*>(&veT[h * 136 + col]) = vv;
    }
#pragma unroll
    for (int kk = 0; kk < 4; ++kk) {         // pe spill as bf16
        bf16x8 pk;
#pragma unroll
        for (int e2 = 0; e2 < 8; ++e2) pk[e2] = (__bf16)peR[kk * 8 + e2];
        *reinterpret_cast<u32x4*>(&peB[il * 136 + part * 32 + kk * 8]) =
            __builtin_bit_cast(u32x4, pk);
    }
    if (part == 0) lrow[il] = lreg;
    __syncthreads();

    // O += pe @ veT   (K = 128; col 127 zero on both sides)
#pragma unroll
    for (int ks = 0; ks < 4; ++ks) {
        bf16x8 pf = __builtin_bit_cast(bf16x8,
            *reinterpret_cast<const u32x4*>(&peB[(w * 16 + c16) * 136 + ks * 32 + g * 8]));
#pragma unroll
        for (int nf2 = 0; nf2 < 4; ++nf2) {
            bf16x8 vf = __builtin_bit_cast(bf16x8,
                *reinterpret_cast<const u32x4*>(&veT[(nf2 * 16 + c16) * 136 + ks * 32 + g * 8]));
            accO[nf2] = __builtin_amdgcn_mfma_f32_16x16x32_bf16(pf, vf, accO[nf2], 0, 0, 0);
        }
    }

    // epilogue: attn_out[b, i, n, h] = O / l
#pragma unroll
    for (int nf2 = 0; nf2 < 4; ++nf2) {
#pragma unroll
        for (int r = 0; r < 4; ++r) {
            int i_l = w * 16 + g * 4 + r;
            int h = nf2 * 16 + c16;
            float vv = accO[nf2][r] / lrow[i_l];
            attn_out[(((size_t)b * 1024 + i0 + i_l) * 16 + (bn & 15)) * 64 + h] = f2bf(vv);
        }
    }
}

// ---------------------------------------------------------------------------
extern "C" void kernel_launch(void* const* d_in, const int* in_sizes, int n_in,
                              void* d_out, int out_size, void* d_ws, size_t ws_size,
                              hipStream_t stream)
{
    const float* x  = (const float*)d_in[0];
    const int* mask = (const int*)d_in[1];
    const float* wq = (const float*)d_in[2];
    const float* wk = (const float*)d_in[3];
    const float* wv = (const float*)d_in[4];
    const float* wo = (const float*)d_in[5];
    const float* qe = (const float*)d_in[6];
    const float* ke = (const float*)d_in[7];
    const float* ve = (const float*)d_in[8];

    char* ws = (char*)d_ws;
    size_t off = 0;
    auto carve = [&](size_t bytes) -> char* {
        char* p = ws + off;
        off += (bytes + 255) & ~(size_t)255;
        return p;
    };
    unsigned short* x_bf    = (unsigned short*)carve(4096ull * 1024 * 2);   //  8 MB
    unsigned short* wqkv_bt = (unsigned short*)carve(3072ull * 1024 * 2);   //  6 MB
    unsigned short* wo_bt   = (unsigned short*)carve(1024ull * 1024 * 2);   //  2 MB
    unsigned short* qe_bf   = (unsigned short*)carve(128ull * 64 * 2);
    unsigned short* ke_bf   = (unsigned short*)carve(128ull * 64 * 2);
    unsigned short* ve_t    = (unsigned short*)carve(64ull * 128 * 2);
    unsigned short* q_buf   = (unsigned short*)carve(65536ull * 64 * 2);    //  8 MB
    unsigned short* k_buf   = (unsigned short*)carve(65536ull * 64 * 2);    //  8 MB
    unsigned short* v_t     = (unsigned short*)carve(65536ull * 64 * 2);    //  8 MB
    unsigned short* q_proj  = (unsigned short*)carve(65536ull * 128 * 2);   // 16 MB
    unsigned short* k_proj  = (unsigned short*)carve(65536ull * 128 * 2);   // 16 MB
    unsigned short* kp_edge = (unsigned short*)carve(2ull * 65536 * 2);     // 256 KB
    unsigned short* attn_o  = x_bf;   // alias: x_bf dead after QKV gemm
    (void)ws_size; (void)in_sizes; (void)n_in; (void)out_size;              // ~72.3 MB

    convert_kernel<<<1537, 256, 0, stream>>>(x, wq, wk, wv, wo, qe, ke, ve,
                                             x_bf, wqkv_bt, wo_bt, qe_bf, ke_bf, ve_t);

    // QKV: [4096,1024] @ [1024,3072]; XCD-swizzled 1D grid
    gemm_qkv_kernel<<<768, 256, 0, stream>>>(
        x_bf, wqkv_bt, q_buf, k_buf, v_t);

    // merged q_proj + k_proj (+ kp_edge): one 1024-block launch
    proj_kernel<<<dim3(1, 1024), 256, 0, stream>>>(
        q_buf, k_buf, qe_bf, ke_bf, q_proj, k_proj, kp_edge);

    // fused attention (async DMA staging + setprio)
    hipFuncSetAttribute((const void*)attn_kernel,
                        hipFuncAttributeMaxDynamicSharedMemorySize, ATTN_LDS_BYTES);
    attn_kernel<<<512, 512, ATTN_LDS_BYTES, stream>>>(
        q_buf, k_buf, v_t, q_proj, k_proj, kp_edge, ve_t, mask, attn_o);

    // output projection: 128x64 tiles, XCD-swizzled 1D grid
    gemm_n64_kernel<<<512, 256, 0, stream>>>(attn_o, wo_bt, (float*)d_out);
}

// Round 15
// 187.985 us; speedup vs baseline: 1.0143x; 1.0143x over previous
//
#include <hip/hip_runtime.h>

// ---------------------------------------------------------------------------
// MultiHeadAttention with clipped relative-position embeddings (q/k/v-side).
// B=4, L=1024, D=1024, N=16, H=64, E=64 (127 distinct distances).
//
// FINAL CONFIGURATION = round-13 verbatim (best measured: 187.87 us total,
// attn 88 us). Round-14 A/B showed: XCD swizzle on QKV/n64 = null-to-negative
// (not L2-locality-bound); s_setprio in attn = null (8 waves barrier-locked
// per tile -> m190 lockstep case, not m191). Both reverted.
//
// Pipeline:
//   0. convert_kernel : region-dispatched, all-coalesced
//   1. gemm_qkv       : QKV GEMM; q/k coalesced scatter; v -> v_t via
//                       in-block LDS transpose (16B-coalesced stores)
//   2. proj_kernel    : q_proj + k_proj in one launch (+ kp_edge)
//   3. attn_kernel    : 8-wave blocks (512 thr), QBLK=128, KVBLK=64,
//                       2 blocks/CU, grid 512 all-resident. Async
//                       global_load_lds staging, double-buffered linear
//                       K/V tiles with src-side XOR swizzle (2-way banks),
//                       kp linear via DMA, 1 barrier/tile steady state.
//                       Register pe-histogram (injective diagonal gather +
//                       rank-1 far-tile bias), zero atomics.
//   4. gemm_n64       : out-proj 128x64 tiles -> fp32 d_out
// Workspace 72.3 MB (attn_o aliased onto dead x_bf).
// ---------------------------------------------------------------------------

typedef __bf16 bf16x8 __attribute__((ext_vector_type(8)));
typedef float f32x4 __attribute__((ext_vector_type(4)));
typedef unsigned int u32x4 __attribute__((ext_vector_type(4)));
typedef unsigned short u16x4 __attribute__((ext_vector_type(4)));

__device__ __forceinline__ unsigned short f2bf(float f) {
    unsigned int u = __builtin_bit_cast(unsigned int, f);
    u += 0x7fffu + ((u >> 16) & 1u);          // RNE
    return (unsigned short)(u >> 16);
}
__device__ __forceinline__ float bf2f(unsigned short s) {
    unsigned int u = ((unsigned int)s) << 16;
    return __builtin_bit_cast(float, u);
}

// async global->LDS, 16 bytes per lane; LDS dest must be wave-uniform base
__device__ __forceinline__ void gl2lds16(const unsigned short* g, unsigned short* l) {
    __builtin_amdgcn_global_load_lds(
        (const __attribute__((address_space(1))) unsigned int*)g,
        (__attribute__((address_space(3))) unsigned int*)l, 16, 0, 0);
}

// ---------------------------------------------------------------------------
// Convert / relayout kernel — all regions coalesced.
// ---------------------------------------------------------------------------
__global__ __launch_bounds__(256) void convert_kernel(
    const float* __restrict__ x,
    const float* __restrict__ wq,
    const float* __restrict__ wk,
    const float* __restrict__ wv,
    const float* __restrict__ wo,
    const float* __restrict__ qe,
    const float* __restrict__ ke,
    const float* __restrict__ ve,
    unsigned short* __restrict__ x_bf,
    unsigned short* __restrict__ wqkv_bt,
    unsigned short* __restrict__ wo_bt,
    unsigned short* __restrict__ qe_bf,
    unsigned short* __restrict__ ke_bf,
    unsigned short* __restrict__ ve_t)
{
    __shared__ unsigned short T[64 * 72];
    const int bid = blockIdx.x;
    const int tid = threadIdx.x;

    if (bid < 512) {
        const float* src = x + (size_t)bid * 8192;
        unsigned short* dst = x_bf + (size_t)bid * 8192;
#pragma unroll
        for (int c = 0; c < 8; ++c) {
            int idx = c * 1024 + tid * 4;
            f32x4 v = *reinterpret_cast<const f32x4*>(src + idx);
            u16x4 o = u16x4{f2bf(v[0]), f2bf(v[1]), f2bf(v[2]), f2bf(v[3])};
            *reinterpret_cast<u16x4*>(dst + idx) = o;
        }
    } else if (bid < 1280) {
        int t = bid - 512;
        int which = t >> 8, n = (t >> 4) & 15, dt = t & 15;
        const float* w = which == 0 ? wq : which == 1 ? wk : wv;
        const float* src = w + ((size_t)n * 1024 + dt * 64) * 64;   // [dd][hh]
#pragma unroll
        for (int c = 0; c < 4; ++c) {
            int chunk = c * 256 + tid;             // 1024 chunks of 4 f32
            int dd = chunk >> 4, hh = (chunk & 15) * 4;
            f32x4 v = *reinterpret_cast<const f32x4*>(src + dd * 64 + hh);
#pragma unroll
            for (int j = 0; j < 4; ++j) T[(hh + j) * 72 + dd] = f2bf(v[j]);
        }
        __syncthreads();
        unsigned short* dstb = wqkv_bt + ((size_t)(which * 1024 + n * 64)) * 1024 + dt * 64;
#pragma unroll
        for (int c = 0; c < 2; ++c) {
            int chunk = c * 256 + tid;             // 512 chunks of 8
            int h = chunk >> 3, d8 = (chunk & 7) * 8;
            u32x4 v = *reinterpret_cast<const u32x4*>(&T[h * 72 + d8]);
            *reinterpret_cast<u32x4*>(dstb + (size_t)h * 1024 + d8) = v;
        }
    } else if (bid < 1536) {
        int t = bid - 1280;
        int n = t >> 4, mt = t & 15;
        const float* src = wo + (size_t)n * 64 * 1024 + mt * 64;    // [hh][mm]
#pragma unroll
        for (int c = 0; c < 4; ++c) {
            int chunk = c * 256 + tid;             // 1024 chunks of 4 f32
            int hh = chunk >> 4, mm = (chunk & 15) * 4;
            f32x4 v = *reinterpret_cast<const f32x4*>(src + (size_t)hh * 1024 + mm);
#pragma unroll
            for (int j = 0; j < 4; ++j) T[(mm + j) * 72 + hh] = f2bf(v[j]);
        }
        __syncthreads();
        unsigned short* dstb = wo_bt + (size_t)(mt * 64) * 1024 + n * 64;
#pragma unroll
        for (int c = 0; c < 2; ++c) {
            int chunk = c * 256 + tid;             // 512 chunks of 8
            int m = chunk >> 3, h8 = (chunk & 7) * 8;
            u32x4 v = *reinterpret_cast<const u32x4*>(&T[m * 72 + h8]);
            *reinterpret_cast<u32x4*>(dstb + (size_t)m * 1024 + h8) = v;
        }
    } else {
        for (int i = tid; i < 8192; i += 256) {
            int e = i >> 6;
            qe_bf[i] = (e < 127) ? f2bf(qe[i]) : 0;
            ke_bf[i] = (e < 127) ? f2bf(ke[i]) : 0;
            int h = i >> 7, e2 = i & 127;
            ve_t[i] = (e2 < 127) ? f2bf(ve[e2 * 64 + h]) : 0;
        }
    }
}

// ---------------------------------------------------------------------------
// QKV GEMM: q/k coalesced scatter; v via LDS transpose.
// ---------------------------------------------------------------------------
__global__ __launch_bounds__(256) void gemm_qkv_kernel(
    const unsigned short* __restrict__ A,
    const unsigned short* __restrict__ Bt,
    unsigned short* __restrict__ q_buf,
    unsigned short* __restrict__ k_buf,
    unsigned short* __restrict__ v_t)
{
    __shared__ unsigned short Sh[2 * 128 * 64];    // As | Bs; reused as T[128][128]
    unsigned short* As = Sh;
    unsigned short* Bs = Sh + 8192;
    const int m0 = blockIdx.y * 128;
    const int n0 = blockIdx.x * 128;
    const int tid = threadIdx.x;
    const int lane = tid & 63;
    const int w = tid >> 6;
    const int wr = w >> 1, wc = w & 1;
    const int g = lane >> 4, c16 = lane & 15;

    f32x4 acc[4][4];
#pragma unroll
    for (int i = 0; i < 4; ++i)
#pragma unroll
        for (int j = 0; j < 4; ++j) acc[i][j] = f32x4{0.f, 0.f, 0.f, 0.f};

    for (int kt = 0; kt < 1024; kt += 64) {
#pragma unroll
        for (int c = 0; c < 4; ++c) {
            int chunk = c * 256 + tid;           // 1024 chunks of 16B
            int row = chunk >> 3, col = (chunk & 7) * 8;
            unsigned short* ldsA = &As[(c * 256 + w * 64) * 8];   // wave-uniform
            unsigned short* ldsB = &Bs[(c * 256 + w * 64) * 8];
            gl2lds16(A  + (size_t)(m0 + row) * 1024 + kt + col, ldsA);
            gl2lds16(Bt + (size_t)(n0 + row) * 1024 + kt + col, ldsB);
        }
        __syncthreads();
#pragma unroll
        for (int ks = 0; ks < 2; ++ks) {
            bf16x8 af[4], bfr[4];
#pragma unroll
            for (int mi = 0; mi < 4; ++mi)
                af[mi] = __builtin_bit_cast(bf16x8,
                    *reinterpret_cast<const u32x4*>(&As[(wr * 64 + mi * 16 + c16) * 64 + ks * 32 + g * 8]));
#pragma unroll
            for (int ni = 0; ni < 4; ++ni)
                bfr[ni] = __builtin_bit_cast(bf16x8,
                    *reinterpret_cast<const u32x4*>(&Bs[(wc * 64 + ni * 16 + c16) * 64 + ks * 32 + g * 8]));
#pragma unroll
            for (int mi = 0; mi < 4; ++mi)
#pragma unroll
                for (int ni = 0; ni < 4; ++ni)
                    acc[mi][ni] = __builtin_amdgcn_mfma_f32_16x16x32_bf16(af[mi], bfr[ni], acc[mi][ni], 0, 0, 0);
        }
        __syncthreads();
    }

    if (n0 < 2048) {
#pragma unroll
        for (int mi = 0; mi < 4; ++mi)
#pragma unroll
            for (int ni = 0; ni < 4; ++ni)
#pragma unroll
                for (int r = 0; r < 4; ++r) {
                    int m = m0 + wr * 64 + mi * 16 + g * 4 + r;
                    int c = n0 + wc * 64 + ni * 16 + c16;
                    int b = m >> 10, l = m & 1023;
                    int which = c >> 10, n = (c >> 6) & 15, h = c & 63;
                    unsigned short* dst = which == 0 ? q_buf : k_buf;
                    dst[(((size_t)b * 16 + n) * 1024 + l) * 64 + h] = f2bf(acc[mi][ni][r]);
                }
    } else {
#pragma unroll
        for (int mi = 0; mi < 4; ++mi)
#pragma unroll
            for (int ni = 0; ni < 4; ++ni)
#pragma unroll
                for (int r = 0; r < 4; ++r) {
                    int l = wr * 64 + mi * 16 + g * 4 + r;
                    int cr = wc * 64 + ni * 16 + c16;
                    Sh[cr * 128 + (l ^ ((cr & 7) << 3))] = f2bf(acc[mi][ni][r]);
                }
        __syncthreads();
        const int b = m0 >> 10;
        const size_t rowbase = (size_t)(b * 1024 + (n0 - 2048)) * 1024 + (m0 & 1023);
#pragma unroll
        for (int c = 0; c < 8; ++c) {
            int chunk = c * 256 + tid;           // 2048 chunks of 8
            int cr = chunk >> 4, l0 = (chunk & 15) * 8;
            int lsw = l0 ^ ((cr & 7) << 3);
            u32x4 vv = *reinterpret_cast<const u32x4*>(&Sh[cr * 128 + lsw]);
            *reinterpret_cast<u32x4*>(v_t + rowbase + (size_t)cr * 1024 + l0) = vv;
        }
    }
}

// ---------------------------------------------------------------------------
// Merged q_proj / k_proj: grid (1, 1024); by<512 -> q, else k (+ kp_edge).
// ---------------------------------------------------------------------------
__global__ __launch_bounds__(256) void proj_kernel(
    const unsigned short* __restrict__ q_buf,
    const unsigned short* __restrict__ k_buf,
    const unsigned short* __restrict__ qe_bf,   // [128][64], row 127 = 0
    const unsigned short* __restrict__ ke_bf,
    unsigned short* __restrict__ q_proj,        // [65536][128]
    unsigned short* __restrict__ k_proj,
    unsigned short* __restrict__ kp_edge)       // [2][65536]
{
    __shared__ unsigned short As[128 * 64];
    __shared__ unsigned short Bs[128 * 64];
    const int by = blockIdx.y;
    const int which = by >> 9;                  // 0 = q, 1 = k
    const int m0 = (by & 511) * 128;
    const unsigned short* A  = which ? k_buf : q_buf;
    const unsigned short* Bt = which ? ke_bf : qe_bf;
    unsigned short* C0 = which ? k_proj : q_proj;

    const int tid = threadIdx.x;
    const int lane = tid & 63;
    const int w = tid >> 6;
    const int wr = w >> 1, wc = w & 1;
    const int g = lane >> 4, c16 = lane & 15;

    f32x4 acc[4][4];
#pragma unroll
    for (int i = 0; i < 4; ++i)
#pragma unroll
        for (int j = 0; j < 4; ++j) acc[i][j] = f32x4{0.f, 0.f, 0.f, 0.f};

#pragma unroll
    for (int c = 0; c < 4; ++c) {
        int chunk = c * 256 + tid;               // 1024 chunks of 16B
        int row = chunk >> 3, col = (chunk & 7) * 8;
        unsigned short* ldsA = &As[(c * 256 + w * 64) * 8];   // wave-uniform
        unsigned short* ldsB = &Bs[(c * 256 + w * 64) * 8];
        gl2lds16(A  + (size_t)(m0 + row) * 64 + col, ldsA);
        gl2lds16(Bt + (size_t)row * 64 + col, ldsB);
    }
    __syncthreads();
#pragma unroll
    for (int ks = 0; ks < 2; ++ks) {
        bf16x8 af[4], bfr[4];
#pragma unroll
        for (int mi = 0; mi < 4; ++mi)
            af[mi] = __builtin_bit_cast(bf16x8,
                *reinterpret_cast<const u32x4*>(&As[(wr * 64 + mi * 16 + c16) * 64 + ks * 32 + g * 8]));
#pragma unroll
        for (int ni = 0; ni < 4; ++ni)
            bfr[ni] = __builtin_bit_cast(bf16x8,
                *reinterpret_cast<const u32x4*>(&Bs[(wc * 64 + ni * 16 + c16) * 64 + ks * 32 + g * 8]));
#pragma unroll
        for (int mi = 0; mi < 4; ++mi)
#pragma unroll
            for (int ni = 0; ni < 4; ++ni)
                acc[mi][ni] = __builtin_amdgcn_mfma_f32_16x16x32_bf16(af[mi], bfr[ni], acc[mi][ni], 0, 0, 0);
    }

#pragma unroll
    for (int mi = 0; mi < 4; ++mi) {
#pragma unroll
        for (int ni = 0; ni < 4; ++ni) {
#pragma unroll
            for (int r = 0; r < 4; ++r) {
                int m = m0 + wr * 64 + mi * 16 + g * 4 + r;
                int c = wc * 64 + ni * 16 + c16;          // n0 = 0, N = 128
                float v = acc[mi][ni][r];
                C0[(size_t)m * 128 + c] = f2bf(v);
                if (which && (c == 0 || c == 126))
                    kp_edge[(size_t)(c ? 65536 : 0) + m] = f2bf(v);
            }
        }
    }
}

// ---------------------------------------------------------------------------
// Out-projection GEMM: [4096,1024] @ wo_bt^T -> fp32, 128x64 tiles.
// ---------------------------------------------------------------------------
__global__ __launch_bounds__(256) void gemm_n64_kernel(
    const unsigned short* __restrict__ A,       // [4096][1024] bf16
    const unsigned short* __restrict__ Bt,      // [1024][1024] bf16
    float* __restrict__ C)                      // [4096][1024] fp32
{
    __shared__ unsigned short As[128 * 64];
    __shared__ unsigned short Bs[64 * 64];
    const int m0 = blockIdx.y * 128;
    const int n0 = blockIdx.x * 64;
    const int tid = threadIdx.x;
    const int lane = tid & 63;
    const int w = tid >> 6;
    const int g = lane >> 4, c16 = lane & 15;

    f32x4 acc[2][4];
#pragma unroll
    for (int i = 0; i < 2; ++i)
#pragma unroll
        for (int j = 0; j < 4; ++j) acc[i][j] = f32x4{0.f, 0.f, 0.f, 0.f};

    for (int kt = 0; kt < 1024; kt += 64) {
#pragma unroll
        for (int c = 0; c < 4; ++c) {            // A: 1024 chunks of 16B
            int chunk = c * 256 + tid;
            int row = chunk >> 3, col = (chunk & 7) * 8;
            unsigned short* ldsA = &As[(c * 256 + w * 64) * 8];
            gl2lds16(A + (size_t)(m0 + row) * 1024 + kt + col, ldsA);
        }
#pragma unroll
        for (int c = 0; c < 2; ++c) {            // B: 512 chunks of 16B
            int chunk = c * 256 + tid;
            int row = chunk >> 3, col = (chunk & 7) * 8;
            unsigned short* ldsB = &Bs[(c * 256 + w * 64) * 8];
            gl2lds16(Bt + (size_t)(n0 + row) * 1024 + kt + col, ldsB);
        }
        __syncthreads();
#pragma unroll
        for (int ks = 0; ks < 2; ++ks) {
            bf16x8 af[2], bfr[4];
#pragma unroll
            for (int mi = 0; mi < 2; ++mi)
                af[mi] = __builtin_bit_cast(bf16x8,
                    *reinterpret_cast<const u32x4*>(&As[(w * 32 + mi * 16 + c16) * 64 + ks * 32 + g * 8]));
#pragma unroll
            for (int ni = 0; ni < 4; ++ni)
                bfr[ni] = __builtin_bit_cast(bf16x8,
                    *reinterpret_cast<const u32x4*>(&Bs[(ni * 16 + c16) * 64 + ks * 32 + g * 8]));
#pragma unroll
            for (int mi = 0; mi < 2; ++mi)
#pragma unroll
                for (int ni = 0; ni < 4; ++ni)
                    acc[mi][ni] = __builtin_amdgcn_mfma_f32_16x16x32_bf16(af[mi], bfr[ni], acc[mi][ni], 0, 0, 0);
        }
        __syncthreads();
    }

#pragma unroll
    for (int mi = 0; mi < 2; ++mi)
#pragma unroll
        for (int ni = 0; ni < 4; ++ni)
#pragma unroll
            for (int r = 0; r < 4; ++r) {
                int m = m0 + w * 32 + mi * 16 + g * 4 + r;
                int cc = n0 + ni * 16 + c16;
                C[(size_t)m * 1024 + cc] = acc[mi][ni][r];
            }
}

// ---------------------------------------------------------------------------
// Fused attention. 512 threads (8 waves), QBLK=128, KVBLK=64, grid 512.
// ASYNC staging via global_load_lds (zero prefetch registers):
//  LDS: KsL[2][64][128B] @0/@8192 (linear, src-swizzled)
//       VtL[2][64][128B] @16384/@24576
//       Ps  [128][72]    @32768   kp [64][128] @51200
//       mjI [2][64] int  @67584   kpeU[2][64] u16 @68096  -> 68352 B
// End overlay: veT@0, peB@17408, lrow@52224.
// Swizzle: LDS chunk c of row r holds global chunk c^(r&7); fragment reads
// XOR chunk with (c16&7) -> 2-way banks (free). 1 barrier/tile steady.
// ---------------------------------------------------------------------------
#define ATTN_LDS_BYTES 68352

__global__ __launch_bounds__(512, 4) void attn_kernel(
    const unsigned short* __restrict__ q_buf,   // [B,N,L,H] bf16
    const unsigned short* __restrict__ k_buf,   // [B,N,L,H] bf16
    const unsigned short* __restrict__ v_t,     // [B,N,H,L] bf16
    const unsigned short* __restrict__ q_proj,  // [B,N,L,128] bf16
    const unsigned short* __restrict__ k_proj,  // [B,N,L,128] bf16
    const unsigned short* __restrict__ kp_edge, // [2][65536] bf16 (e=0,126)
    const unsigned short* __restrict__ ve_t,    // [64][128] bf16 (col 127 = 0)
    const int* __restrict__ mask,               // [B,1024]
    unsigned short* __restrict__ attn_out)      // [B,L,N,H] bf16
{
    extern __shared__ char smem[];
    unsigned short* Ps   = (unsigned short*)(smem + 32768); // [128][72]
    unsigned short* kp   = (unsigned short*)(smem + 51200); // [64][128]
    int*            mjI  = (int*)(smem + 67584);            // [2][64]
    unsigned short* kpeU = (unsigned short*)(smem + 68096); // [2][64]
    unsigned short* veT = (unsigned short*)smem;            // [64][136] overlay
    unsigned short* peB = (unsigned short*)(smem + 17408);  // [128][136] overlay
    float* lrow = (float*)(smem + 52224);                   // [128]

    const int id = blockIdx.x;
    const int bn = id & 63;                  // = b*16 + n (same XCD per group)
    const int ib = id >> 6;                  // i-block, 128 rows
    const int b = bn >> 4;
    const int i0 = ib * 128;
    const int tid = threadIdx.x;
    const int lane = tid & 63;
    const int w = tid >> 6;                  // wave 0..7, rows [w*16,w*16+16)
    const int g = lane >> 4, c16 = lane & 15;
    const int il = tid >> 2;                 // histogram row 0..127
    const int part = tid & 3;                // bins [part*32, part*32+32)
    const int swz = c16 & 7;                 // fragment-read chunk XOR

    const int jlo = 2 * ib - 1, jhi = 2 * ib + 2;   // kp window

    // DMA geometry: wave w covers rows [w*8, w*8+8) of a [64][128B] tile
    const int srow = w * 8 + (lane >> 3);
    const int gch  = (lane & 7) ^ (srow & 7);       // pre-swizzled chunk

    auto issue_kv = [&](int j0n, int nxt) {
        gl2lds16(k_buf + ((size_t)bn * 1024 + j0n + srow) * 64 + gch * 8,
                 (unsigned short*)(smem + nxt * 8192) + w * 512);
        gl2lds16(v_t + ((size_t)bn * 64 + srow) * 1024 + j0n + gch * 8,
                 (unsigned short*)(smem + 16384 + nxt * 8192) + w * 512);
    };
    auto stage_scalar = [&](int jtn, int nxt) {     // waves 0/1, plain ld+st
        int j0n = jtn * 64;
        if (w == 0) mjI[nxt * 64 + lane] = mask[b * 1024 + j0n + lane];
        if (w == 1) kpeU[nxt * 64 + lane] =
            kp_edge[(size_t)(jtn < 2 * ib ? 65536 : 0) + bn * 1024 + j0n + lane];
    };
    auto issue_kp = [&](int jtn) {                  // [64][128] linear, 16 KB
        int j0n = jtn * 64;
#pragma unroll
        for (int c = 0; c < 2; ++c) {
            int chunk = w * 128 + c * 64 + lane;
            int row = chunk >> 4, col8 = chunk & 15;
            gl2lds16(k_proj + ((size_t)bn * 1024 + j0n + row) * 128 + col8 * 8,
                     kp + (w * 128 + c * 64) * 8);
        }
    };

    // prologue: tile 0 in flight
    issue_kv(0, 0);
    stage_scalar(0, 0);
    if (0 >= jlo && 0 <= jhi) issue_kp(0);

    // Q fragments + loop-invariant qp edge columns (overlap tile-0 latency)
    bf16x8 qf[2];
    {
        const unsigned short* qrow = q_buf + ((size_t)bn * 1024 + i0 + w * 16 + c16) * 64;
        qf[0] = __builtin_bit_cast(bf16x8, *reinterpret_cast<const u32x4*>(qrow + g * 8));
        qf[1] = __builtin_bit_cast(bf16x8, *reinterpret_cast<const u32x4*>(qrow + 32 + g * 8));
    }
    f32x4 qp0v, qp126v;
#pragma unroll
    for (int r = 0; r < 4; ++r) {
        size_t row = (size_t)bn * 1024 + i0 + w * 16 + g * 4 + r;
        qp0v[r]   = 0.125f * bf2f(q_proj[row * 128 + 0]);
        qp126v[r] = 0.125f * bf2f(q_proj[row * 128 + 126]);
    }

    float peR[32];
#pragma unroll
    for (int k = 0; k < 32; ++k) peR[k] = 0.f;
    float lreg = 0.f, acc0 = 0.f, acc126 = 0.f;
    f32x4 accO[4];
#pragma unroll
    for (int i = 0; i < 4; ++i) accO[i] = f32x4{0.f, 0.f, 0.f, 0.f};

    __syncthreads();                          // tile 0 resident

    for (int jt = 0; jt < 16; ++jt) {
        const int cur = jt & 1;
        const int j0 = jt * 64;
        const unsigned short* Ksc = (const unsigned short*)(smem + cur * 8192);
        const unsigned short* Vtc = (const unsigned short*)(smem + 16384 + cur * 8192);

        if (jt < 15) {                        // async prefetch of jt+1
            issue_kv(j0 + 64, cur ^ 1);
            stage_scalar(jt + 1, cur ^ 1);
        }

        // ---- S = Q K^T (swizzled fragment reads) ----
        f32x4 sacc[4];
#pragma unroll
        for (int nf = 0; nf < 4; ++nf) sacc[nf] = f32x4{0.f, 0.f, 0.f, 0.f};
#pragma unroll
        for (int ks = 0; ks < 2; ++ks)
#pragma unroll
            for (int nf = 0; nf < 4; ++nf) {
                bf16x8 kf = __builtin_bit_cast(bf16x8,
                    *reinterpret_cast<const u32x4*>(&Ksc[(nf * 16 + c16) * 64 + ((ks * 4 + g) ^ swz) * 8]));
                sacc[nf] = __builtin_amdgcn_mfma_f32_16x16x32_bf16(qf[ks], kf, sacc[nf], 0, 0, 0);
            }

        // ---- bias + exp + P store (wave-uniform near/far decision) ----
        const int dw = i0 + w * 16 - j0;
        if (dw < 126 && dw > -78) {
            const int d0 = i0 - j0 + 63;
            const unsigned short* qpg = q_proj + ((size_t)bn * 1024 + i0) * 128;
#pragma unroll
            for (int nf = 0; nf < 4; ++nf) {
                int j_l = nf * 16 + c16;
                float mfl = mjI[cur * 64 + j_l] ? 1.f : 0.f;
#pragma unroll
                for (int r = 0; r < 4; ++r) {
                    int i_l = w * 16 + g * 4 + r;
                    int e = d0 + i_l - j_l;
                    e = e < 0 ? 0 : (e > 126 ? 126 : e);
                    float s = sacc[nf][r] + bf2f(kp[j_l * 128 + e]) + bf2f(qpg[i_l * 128 + e]);
                    s *= 0.125f;
                    float p = (mfl > 0.f) ? __expf(s) : 0.f;
                    Ps[i_l * 72 + j_l] = f2bf(p);
                }
            }
        } else {
            const f32x4 qpc = (dw >= 126) ? qp126v : qp0v;
#pragma unroll
            for (int nf = 0; nf < 4; ++nf) {
                int j_l = nf * 16 + c16;
                float kv = 0.125f * bf2f(kpeU[cur * 64 + j_l]);
                float mfl = mjI[cur * 64 + j_l] ? 1.f : 0.f;
#pragma unroll
                for (int r = 0; r < 4; ++r) {
                    float s = sacc[nf][r] * 0.125f + kv + qpc[r];
                    float p = (mfl > 0.f) ? __expf(s) : 0.f;
                    Ps[(w * 16 + g * 4 + r) * 72 + j_l] = f2bf(p);
                }
            }
        }

        // ---- O += P @ V (Ps rows wave-private; lgkmcnt orders RAW) ----
#pragma unroll
        for (int ks = 0; ks < 2; ++ks) {
            bf16x8 pf = __builtin_bit_cast(bf16x8,
                *reinterpret_cast<const u32x4*>(&Ps[(w * 16 + c16) * 72 + ks * 32 + g * 8]));
#pragma unroll
            for (int nf2 = 0; nf2 < 4; ++nf2) {
                bf16x8 vf = __builtin_bit_cast(bf16x8,
                    *reinterpret_cast<const u32x4*>(&Vtc[(nf2 * 16 + c16) * 64 + ((ks * 4 + g) ^ swz) * 8]));
                accO[nf2] = __builtin_amdgcn_mfma_f32_16x16x32_bf16(pf, vf, accO[nf2], 0, 0, 0);
            }
        }

        // ---- pe histogram (register bins; per-row near/far) ----
        {
            bf16x8 s0 = __builtin_bit_cast(bf16x8,
                *reinterpret_cast<const u32x4*>(&Ps[il * 72 + part * 16]));
            bf16x8 s1 = __builtin_bit_cast(bf16x8,
                *reinterpret_cast<const u32x4*>(&Ps[il * 72 + part * 16 + 8]));
            float v[16];
#pragma unroll
            for (int m = 0; m < 8; ++m) { v[m] = (float)s0[m]; v[8 + m] = (float)s1[m]; }
            float rs = 0.f;
#pragma unroll
            for (int m = 0; m < 16; ++m) rs += v[m];
            rs += __shfl_xor(rs, 1);
            rs += __shfl_xor(rs, 2);
            lreg += rs;

            const int base = i0 + il - j0 + 63;   // jl for bin e is base - e
            if (base >= 189) {
                acc126 += rs;
            } else if (base <= 0) {
                acc0 += rs;
            } else {
                float b0 = 0.f, b126 = 0.f;
#pragma unroll
                for (int m = 0; m < 16; ++m) {
                    int jl = part * 16 + m;
                    if (jl >= base) b0 += v[m];
                    if (jl <= base - 126) b126 += v[m];
                }
                b0 += __shfl_xor(b0, 1);     b0 += __shfl_xor(b0, 2);
                b126 += __shfl_xor(b126, 1); b126 += __shfl_xor(b126, 2);
                if (part == 0) peR[0] += b0;
                if (part == 3) peR[30] += b126;
#pragma unroll
                for (int k = 0; k < 32; ++k) {
                    int e = part * 32 + k;
                    int jl = base - e;
                    if (e >= 1 && e <= 125 && jl >= 0 && jl < 64)
                        peR[k] += bf2f(Ps[il * 72 + jl]);
                }
            }
        }

        // ---- end of tile: one barrier; kp-window tiles take an extra ----
        const bool kpn = (jt < 15) && (jt + 1 >= jlo) && (jt + 1 <= jhi);
        __syncthreads();                     // drains prefetch; frees kp/Ps
        if (kpn) {
            issue_kp(jt + 1);                // kp readers (tile jt) done
            __syncthreads();                 // kp(jt+1) resident
        }
    }

    if (part == 0) peR[0] += acc0;
    if (part == 3) peR[30] += acc126;

    // ---- end phase: overlay veT/peB/lrow on dead staging ----
#pragma unroll
    for (int c = 0; c < 2; ++c) {
        int chunk = tid + c * 512;           // 1024 chunks of 8 elems = 64x128
        int h = chunk >> 4, col = (chunk & 15) * 8;
        u32x4 vv = *reinterpret_cast<const u32x4*>(ve_t + h * 128 + col);
        *reinterpret_cast<u32x4*>(&veT[h * 136 + col]) = vv;
    }
#pragma unroll
    for (int kk = 0; kk < 4; ++kk) {         // pe spill as bf16
        bf16x8 pk;
#pragma unroll
        for (int e2 = 0; e2 < 8; ++e2) pk[e2] = (__bf16)peR[kk * 8 + e2];
        *reinterpret_cast<u32x4*>(&peB[il * 136 + part * 32 + kk * 8]) =
            __builtin_bit_cast(u32x4, pk);
    }
    if (part == 0) lrow[il] = lreg;
    __syncthreads();

    // O += pe @ veT   (K = 128; col 127 zero on both sides)
#pragma unroll
    for (int ks = 0; ks < 4; ++ks) {
        bf16x8 pf = __builtin_bit_cast(bf16x8,
            *reinterpret_cast<const u32x4*>(&peB[(w * 16 + c16) * 136 + ks * 32 + g * 8]));
#pragma unroll
        for (int nf2 = 0; nf2 < 4; ++nf2) {
            bf16x8 vf = __builtin_bit_cast(bf16x8,
                *reinterpret_cast<const u32x4*>(&veT[(nf2 * 16 + c16) * 136 + ks * 32 + g * 8]));
            accO[nf2] = __builtin_amdgcn_mfma_f32_16x16x32_bf16(pf, vf, accO[nf2], 0, 0, 0);
        }
    }

    // epilogue: attn_out[b, i, n, h] = O / l
#pragma unroll
    for (int nf2 = 0; nf2 < 4; ++nf2) {
#pragma unroll
        for (int r = 0; r < 4; ++r) {
            int i_l = w * 16 + g * 4 + r;
            int h = nf2 * 16 + c16;
            float vv = accO[nf2][r] / lrow[i_l];
            attn_out[(((size_t)b * 1024 + i0 + i_l) * 16 + (bn & 15)) * 64 + h] = f2bf(vv);
        }
    }
}

// ---------------------------------------------------------------------------
extern "C" void kernel_launch(void* const* d_in, const int* in_sizes, int n_in,
                              void* d_out, int out_size, void* d_ws, size_t ws_size,
                              hipStream_t stream)
{
    const float* x  = (const float*)d_in[0];
    const int* mask = (const int*)d_in[1];
    const float* wq = (const float*)d_in[2];
    const float* wk = (const float*)d_in[3];
    const float* wv = (const float*)d_in[4];
    const float* wo = (const float*)d_in[5];
    const float* qe = (const float*)d_in[6];
    const float* ke = (const float*)d_in[7];
    const float* ve = (const float*)d_in[8];

    char* ws = (char*)d_ws;
    size_t off = 0;
    auto carve = [&](size_t bytes) -> char* {
        char* p = ws + off;
        off += (bytes + 255) & ~(size_t)255;
        return p;
    };
    unsigned short* x_bf    = (unsigned short*)carve(4096ull * 1024 * 2);   //  8 MB
    unsigned short* wqkv_bt = (unsigned short*)carve(3072ull * 1024 * 2);   //  6 MB
    unsigned short* wo_bt   = (unsigned short*)carve(1024ull * 1024 * 2);   //  2 MB
    unsigned short* qe_bf   = (unsigned short*)carve(128ull * 64 * 2);
    unsigned short* ke_bf   = (unsigned short*)carve(128ull * 64 * 2);
    unsigned short* ve_t    = (unsigned short*)carve(64ull * 128 * 2);
    unsigned short* q_buf   = (unsigned short*)carve(65536ull * 64 * 2);    //  8 MB
    unsigned short* k_buf   = (unsigned short*)carve(65536ull * 64 * 2);    //  8 MB
    unsigned short* v_t     = (unsigned short*)carve(65536ull * 64 * 2);    //  8 MB
    unsigned short* q_proj  = (unsigned short*)carve(65536ull * 128 * 2);   // 16 MB
    unsigned short* k_proj  = (unsigned short*)carve(65536ull * 128 * 2);   // 16 MB
    unsigned short* kp_edge = (unsigned short*)carve(2ull * 65536 * 2);     // 256 KB
    unsigned short* attn_o  = x_bf;   // alias: x_bf dead after QKV gemm
    (void)ws_size; (void)in_sizes; (void)n_in; (void)out_size;              // ~72.3 MB

    convert_kernel<<<1537, 256, 0, stream>>>(x, wq, wk, wv, wo, qe, ke, ve,
                                             x_bf, wqkv_bt, wo_bt, qe_bf, ke_bf, ve_t);

    // QKV: [4096,1024] @ [1024,3072]; v transposed via LDS (coalesced)
    gemm_qkv_kernel<<<dim3(24, 32), 256, 0, stream>>>(
        x_bf, wqkv_bt, q_buf, k_buf, v_t);

    // merged q_proj + k_proj (+ kp_edge): one 1024-block launch
    proj_kernel<<<dim3(1, 1024), 256, 0, stream>>>(
        q_buf, k_buf, qe_bf, ke_bf, q_proj, k_proj, kp_edge);

    // fused attention (async DMA staging, 1 barrier/tile steady state)
    hipFuncSetAttribute((const void*)attn_kernel,
                        hipFuncAttributeMaxDynamicSharedMemorySize, ATTN_LDS_BYTES);
    attn_kernel<<<512, 512, ATTN_LDS_BYTES, stream>>>(
        q_buf, k_buf, v_t, q_proj, k_proj, kp_edge, ve_t, mask, attn_o);

    // output projection: 128x64 tiles, 512 blocks = 2/CU
    gemm_n64_kernel<<<dim3(16, 32), 256, 0, stream>>>(attn_o, wo_bt, (float*)d_out);
}